// Round 5
// baseline (388.237 us; speedup 1.0000x reference)
//
#include <hip/hip_runtime.h>

#define NN 100000
#define ENUM 25000
#define NNZ_C 200000
// D = 128, H = 4, F = 128, Wlin: [128,512]
// Interleaved feature layout: [row][f][h] (f=0..127, h=0..3)

typedef __attribute__((ext_vector_type(8))) short bf16x8;
typedef __attribute__((ext_vector_type(4))) float f32x4;

__device__ __forceinline__ float bf2f(unsigned short v) {
    return __uint_as_float(((unsigned)v) << 16);
}
__device__ __forceinline__ float blo(unsigned u) { return __uint_as_float(u << 16); }
__device__ __forceinline__ float bhi(unsigned u) { return __uint_as_float(u & 0xFFFF0000u); }
__device__ __forceinline__ unsigned short f2bf(float x) {
    unsigned u = __float_as_uint(x);
    unsigned r = (u + 0x7fff + ((u >> 16) & 1)) >> 16;   // round-to-nearest-even
    return (unsigned short)r;
}

// -------- f32 -> bf16 convert (4 elems/thread) --------
__global__ __launch_bounds__(256) void convbf_k(
    const float* __restrict__ in, unsigned short* __restrict__ out, int n4)
{
    const int t = blockIdx.x * 256 + threadIdx.x;
    if (t >= n4) return;
    const float4 a = ((const float4*)in)[t];
    ushort4 u;
    u.x = f2bf(a.x); u.y = f2bf(a.y); u.z = f2bf(a.z); u.w = f2bf(a.w);
    ((ushort4*)out)[t] = u;
}

// -------- W[128][NC] f32 -> Wt[NC][128] bf16 (transpose) --------
__global__ __launch_bounds__(256) void wtr_k(
    const float* __restrict__ W, unsigned short* __restrict__ Wt, int NC)
{
    const int t = blockIdx.x * 256 + threadIdx.x;
    if (t >= 128 * NC) return;
    const int c = t % NC, k = t / NC;
    Wt[c * 128 + k] = f2bf(W[t]);
}

// ---------------- MFMA GEMM: C[M,NC] = A[M,128] @ W[128,NC] (+bias)(+resid) ----
// PERM: store column c at position (c&127)*4 + (c>>7)   ([r][f][h] layout, NC=512)
template <bool BF16OUT, bool PERM>
__global__ __launch_bounds__(256) void gemm_mfma_k(
    const unsigned short* __restrict__ A, const unsigned short* __restrict__ Wt,
    const float* __restrict__ bias, const float* __restrict__ resid,
    void* __restrict__ Cv, int M, int NC)
{
    __shared__ unsigned short As[64 * 128];
    __shared__ unsigned short Bs[64 * 128];
    const int tid = threadIdx.x;
    const int r0 = blockIdx.x * 64;
    const int c0 = blockIdx.y * 64;

    {
        int rr = tid >> 4;
        const int kc = (tid & 15) * 8;
        #pragma unroll
        for (int it = 0; it < 4; it++) {
            int r = r0 + rr; if (r > M - 1) r = M - 1;
            const uint4 va = *(const uint4*)(A + (size_t)r * 128 + kc);
            const uint4 vb = *(const uint4*)(Wt + (size_t)(c0 + rr) * 128 + kc);
            const int idx = (rr * 128 + kc) ^ ((rr & 7) << 3);
            *(uint4*)&As[idx] = va;
            *(uint4*)&Bs[idx] = vb;
            rr += 16;
        }
    }
    __syncthreads();

    const int lane = tid & 63;
    const int wid = tid >> 6;
    const int wr = wid >> 1, wc = wid & 1;
    const int fr = lane & 15;
    const int kg = (lane >> 4) * 8;

    f32x4 acc[2][2] = {};

    #pragma unroll
    for (int ks = 0; ks < 4; ks++) {
        bf16x8 a[2], b[2];
        #pragma unroll
        for (int m = 0; m < 2; m++) {
            const int ar = wr * 32 + m * 16 + fr;
            const int idx = (ar * 128 + ks * 32 + kg) ^ ((ar & 7) << 3);
            a[m] = *(const bf16x8*)&As[idx];
        }
        #pragma unroll
        for (int n = 0; n < 2; n++) {
            const int br = wc * 32 + n * 16 + fr;
            const int idx = (br * 128 + ks * 32 + kg) ^ ((br & 7) << 3);
            b[n] = *(const bf16x8*)&Bs[idx];
        }
        #pragma unroll
        for (int m = 0; m < 2; m++)
            #pragma unroll
            for (int n = 0; n < 2; n++)
                acc[m][n] = __builtin_amdgcn_mfma_f32_16x16x32_bf16(a[m], b[n], acc[m][n], 0, 0, 0);
    }

    #pragma unroll
    for (int m = 0; m < 2; m++) {
        #pragma unroll
        for (int n = 0; n < 2; n++) {
            const int c = c0 + wc * 32 + n * 16 + (lane & 15);
            const int cc = PERM ? ((c & 127) * 4 + (c >> 7)) : c;
            #pragma unroll
            for (int j = 0; j < 4; j++) {
                const int r = r0 + wr * 32 + m * 16 + (lane >> 4) * 4 + j;
                if (r < M) {
                    float v = acc[m][n][j];
                    if (bias) v += bias[c];
                    if (resid) v += resid[(size_t)r * NC + c];
                    if (BF16OUT) ((unsigned short*)Cv)[(size_t)r * NC + cc] = f2bf(v);
                    else         ((float*)Cv)[(size_t)r * NC + cc] = v;
                }
            }
        }
    }
}

// -------- edge aggregation: Eres[e,:] += (1/deg_e) * sum_j adj[k] * Xt[row[k],:] ----
__global__ __launch_bounds__(256) void edge_agg_k(
    const int* __restrict__ row, const float* __restrict__ adjv,
    const unsigned short* __restrict__ Xt, float* __restrict__ Eres)
{
    const int e = blockIdx.x * 2 + (threadIdx.x >> 7);
    const int f = threadIdx.x & 127;
    if (e >= ENUM) return;
    float acc = 0.f, deg = 0.f;
    #pragma unroll
    for (int j = 0; j < 8; j++) {
        const int k = e + j * ENUM;
        const float v = adjv[k];
        deg += v;
        acc += v * bf2f(Xt[(size_t)row[k] * 128 + f]);
    }
    Eres[(size_t)e * 128 + f] += acc / deg;
}

// -------- attention dot on [r][f][h] layout: one wave per row ----
// out[r*4+h] = sum_f feat[r][f][h] * att[h*256+f]
__global__ __launch_bounds__(256) void att_dot_fh_k(
    const unsigned short* __restrict__ feat, const float* __restrict__ att,
    float* __restrict__ out, int M)
{
    const int r = blockIdx.x * 4 + (threadIdx.x >> 6);
    const int lane = threadIdx.x & 63;
    if (r >= M) return;
    const int f0 = lane * 2;
    const uint4 u = *(const uint4*)(feat + (size_t)r * 512 + f0 * 4);
    float s0 = blo(u.x) * att[f0]       + blo(u.z) * att[f0 + 1];
    float s1 = bhi(u.x) * att[256 + f0] + bhi(u.z) * att[256 + f0 + 1];
    float s2 = blo(u.y) * att[512 + f0] + blo(u.w) * att[512 + f0 + 1];
    float s3 = bhi(u.y) * att[768 + f0] + bhi(u.w) * att[768 + f0 + 1];
    #pragma unroll
    for (int off = 1; off < 64; off <<= 1) {
        s0 += __shfl_xor(s0, off);
        s1 += __shfl_xor(s1, off);
        s2 += __shfl_xor(s2, off);
        s3 += __shfl_xor(s3, off);
    }
    if (lane == 0) *(float4*)(out + (size_t)r * 4) = make_float4(s0, s1, s2, s3);
}

// -------- CSR build --------
__global__ __launch_bounds__(256) void zero_k(unsigned* __restrict__ p, int n)
{
    const int t = blockIdx.x * 256 + threadIdx.x;
    if (t < n) p[t] = 0u;
}

__global__ __launch_bounds__(256) void hist_k(
    const int* __restrict__ row, int* __restrict__ cnt)
{
    const int k = blockIdx.x * 256 + threadIdx.x;
    if (k < NNZ_C) atomicAdd(cnt + row[k], 1);
}

__global__ __launch_bounds__(256) void scan1_k(
    const int* __restrict__ cnt, int* __restrict__ rp, int* __restrict__ bsum, int n)
{
    __shared__ int sh[256];
    const int t = threadIdx.x, g = blockIdx.x * 256 + t;
    const int v = (g < n) ? cnt[g] : 0;
    sh[t] = v; __syncthreads();
    #pragma unroll
    for (int off = 1; off < 256; off <<= 1) {
        const int add = (t >= off) ? sh[t - off] : 0;
        __syncthreads();
        sh[t] += add;
        __syncthreads();
    }
    if (g < n) rp[g] = sh[t] - v;
    if (t == 255) bsum[blockIdx.x] = sh[255];
}

__global__ __launch_bounds__(512) void scan2_k(int* __restrict__ bsum, int nb)
{
    __shared__ int sh[512];
    const int t = threadIdx.x;
    const int v = (t < nb) ? bsum[t] : 0;
    sh[t] = v; __syncthreads();
    #pragma unroll
    for (int off = 1; off < 512; off <<= 1) {
        const int add = (t >= off) ? sh[t - off] : 0;
        __syncthreads();
        sh[t] += add;
        __syncthreads();
    }
    if (t < nb) bsum[t] = sh[t] - v;
}

__global__ __launch_bounds__(256) void scan3_k(
    int* __restrict__ rp, const int* __restrict__ bsum, int* __restrict__ cur, int n)
{
    const int g = blockIdx.x * 256 + threadIdx.x;
    if (g < n) {
        const int v = rp[g] + bsum[g >> 8];
        rp[g] = v;
        cur[g] = v;
    }
    if (g == 0) rp[n] = NNZ_C;
}

__global__ __launch_bounds__(256) void fill_k(
    const int* __restrict__ row, int* __restrict__ cur, int* __restrict__ eidx)
{
    const int k = blockIdx.x * 256 + threadIdx.x;
    if (k < NNZ_C) {
        const int p = atomicAdd(cur + row[k], 1);
        eidx[p] = k;
    }
}

// -------- CSR segment softmax; emits alpha (k-order) AND alphag (CSR p-order) ----
__global__ __launch_bounds__(256) void softmax_csr_k(
    const int* __restrict__ rowptr, const int* __restrict__ eidx,
    const float* __restrict__ ax, const float* __restrict__ ae,
    float* __restrict__ alpha, float* __restrict__ alphag)
{
    const int t = blockIdx.x * 256 + threadIdx.x;
    if (t >= NN * 4) return;
    const int r = t >> 2, h = t & 3;
    const int p0 = rowptr[r], p1 = rowptr[r + 1];
    if (p0 == p1) return;
    const float axv = ax[t];
    float m = -1e30f;
    for (int p = p0; p < p1; ++p) {
        const int c = eidx[p] % ENUM;           // col[k] == k % EN by construction
        float a = axv + ae[c * 4 + h];
        a = (a >= 0.f) ? a : 0.2f * a;
        m = fmaxf(m, a);
    }
    float s = 0.f;
    for (int p = p0; p < p1; ++p) {
        const int k = eidx[p];
        const int c = k % ENUM;
        float a = axv + ae[c * 4 + h];
        a = (a >= 0.f) ? a : 0.2f * a;
        const float e = __expf(a - m);
        s += e;
        alpha[(size_t)k * 4 + h] = e;
    }
    const float rs = 1.f / s;
    for (int p = p0; p < p1; ++p) {
        const int k = eidx[p];
        const float v = alpha[(size_t)k * 4 + h] * rs;
        alpha[(size_t)k * 4 + h] = v;
        alphag[((size_t)p << 2) | h] = v;
    }
}

// -------- out_e[e][f][h] = (1/8) sum_j alpha[k,h] * Xlin[row[k]][f][h]  (bf16) ----
__global__ __launch_bounds__(256) void out_e_k(
    const int* __restrict__ row, const float* __restrict__ alpha,
    const unsigned short* __restrict__ Xlin, unsigned short* __restrict__ out_e)
{
    const int e = blockIdx.x * 4 + (threadIdx.x >> 6);
    const int lane = threadIdx.x & 63;
    if (e >= ENUM) return;
    const int f0 = lane * 2;
    float a0 = 0.f, a1 = 0.f, a2 = 0.f, a3 = 0.f;
    float a4 = 0.f, a5 = 0.f, a6 = 0.f, a7 = 0.f;
    #pragma unroll
    for (int j = 0; j < 8; j++) {
        const int k = e + j * ENUM;
        const int r = row[k];
        const float4 al = *(const float4*)(alpha + (size_t)k * 4);
        const uint4 u = *(const uint4*)(Xlin + (size_t)r * 512 + f0 * 4);
        a0 += al.x * blo(u.x); a1 += al.y * bhi(u.x);
        a2 += al.z * blo(u.y); a3 += al.w * bhi(u.y);
        a4 += al.x * blo(u.z); a5 += al.y * bhi(u.z);
        a6 += al.z * blo(u.w); a7 += al.w * bhi(u.w);
    }
    uint4 o;
    o.x = (unsigned)f2bf(0.125f * a0) | ((unsigned)f2bf(0.125f * a1) << 16);
    o.y = (unsigned)f2bf(0.125f * a2) | ((unsigned)f2bf(0.125f * a3) << 16);
    o.z = (unsigned)f2bf(0.125f * a4) | ((unsigned)f2bf(0.125f * a5) << 16);
    o.w = (unsigned)f2bf(0.125f * a6) | ((unsigned)f2bf(0.125f * a7) << 16);
    *(uint4*)(out_e + (size_t)e * 512 + f0 * 4) = o;
}

// -------- final CSR gather: one wave per node, 2 f per lane, unroll-2 over edges ----
__global__ __launch_bounds__(256) void xgather_k(
    const int* __restrict__ rowptr, const int* __restrict__ eidx,
    const float* __restrict__ adjv, const float* __restrict__ alphag,
    const unsigned short* __restrict__ out_e, const float* __restrict__ bias,
    float* __restrict__ Xres)
{
    const int r = blockIdx.x * 4 + (threadIdx.x >> 6);
    const int lane = threadIdx.x & 63;
    if (r >= NN) return;
    const int p0 = rowptr[r], p1 = rowptr[r + 1];
    const int f0 = lane * 2;
    float a0 = 0.f, a1 = 0.f, ds = 0.f;

#define XG_BODY(P) {                                                          \
        const int k = eidx[P];                                                \
        const int c = k % ENUM;                                               \
        ds += adjv[c];                                                        \
        const float4 al = *(const float4*)(alphag + ((size_t)(P) << 2));      \
        const uint4 u = *(const uint4*)(out_e + (size_t)c * 512 + f0 * 4);    \
        a0 += al.x * blo(u.x) + al.y * bhi(u.x) + al.z * blo(u.y) + al.w * bhi(u.y); \
        a1 += al.x * blo(u.z) + al.y * bhi(u.z) + al.z * blo(u.w) + al.w * bhi(u.w); \
    }

    int p = p0;
    for (; p + 2 <= p1; p += 2) { XG_BODY(p); XG_BODY(p + 1); }
    if (p < p1) XG_BODY(p);
#undef XG_BODY

    const float w = (p1 > p0) ? 0.25f / ds : 0.f;
    float2 o;
    o.x = bias[f0] + w * a0;
    o.y = bias[f0 + 1] + w * a1;
    *(float2*)(Xres + (size_t)r * 128 + f0) = o;
}

extern "C" void kernel_launch(void* const* d_in, const int* in_sizes, int n_in,
                              void* d_out, int out_size, void* d_ws, size_t ws_size,
                              hipStream_t stream)
{
    const float* X         = (const float*)d_in[0];
    const float* E         = (const float*)d_in[1];
    const int*   adj       = (const int*)d_in[2];
    const float* adjv      = (const float*)d_in[3];
    const float* Wn        = (const float*)d_in[4];
    const float* bn        = (const float*)d_in[5];
    const float* We        = (const float*)d_in[6];
    const float* be        = (const float*)d_in[7];
    const float* Wlin      = (const float*)d_in[8];
    const float* att       = (const float*)d_in[9];
    const float* bias_conv = (const float*)d_in[10];
    const int* row = adj;

    float* Xres = (float*)d_out;
    float* Eres = Xres + (size_t)NN * 128;

    // workspace layout (~167 MB)
    char* wsb = (char*)d_ws;
    unsigned short* Xbf   = (unsigned short*)(wsb);              // [0, 25.6M)
    unsigned short* elin  = (unsigned short*)(wsb);              // aliases Xbf (after gemm4)
    unsigned short* out_e = (unsigned short*)(wsb);              // aliases elin (after att_dot_e)
    unsigned short* Xt    = (unsigned short*)(wsb + 25600000);   // [25.6M, 51.2M)
    unsigned short* EresB = (unsigned short*)(wsb + 25600000);   // aliases Xt (after edge_agg)
    float*          alphag= (float*)(wsb + 25600000);            // aliases EresB (after gemm5)
    unsigned short* Xlin  = (unsigned short*)(wsb + 51200000);   // 102.4 MB
    unsigned short* Ebf   = (unsigned short*)(wsb + 153600000);  // 6.4 MB
    unsigned short* WlinT = (unsigned short*)(wsb + 160000000);  // 128 KB
    unsigned short* WnT   = (unsigned short*)(wsb + 160131072);  // 32 KB
    unsigned short* WeT   = (unsigned short*)(wsb + 160163840);  // 32 KB
    float* ax    = (float*)(wsb + 160196608);                    // 1.6 MB
    float* ae    = (float*)(wsb + 161796608);                    // 0.4 MB
    float* alpha = (float*)(wsb + 162196608);                    // 3.2 MB
    int* rowptr  = (int*)(wsb + 165396608);                      // 400,016 B
    int* cnt     = (int*)(wsb + 165796624);                      // 400,000 B (reused as cursor)
    int* eidx    = (int*)(wsb + 166196624);                      // 800,000 B
    int* bsum    = (int*)(wsb + 166996624);                      // 2 KB

    // ---- CSR build (independent of GEMMs) ----
    zero_k<<<(NN + 255) / 256, 256, 0, stream>>>((unsigned*)cnt, NN);
    hist_k<<<(NNZ_C + 255) / 256, 256, 0, stream>>>(row, cnt);
    scan1_k<<<(NN + 255) / 256, 256, 0, stream>>>(cnt, rowptr, bsum, NN);
    scan2_k<<<1, 512, 0, stream>>>(bsum, (NN + 255) / 256);
    scan3_k<<<(NN + 255) / 256, 256, 0, stream>>>(rowptr, bsum, cnt, NN);
    fill_k<<<(NNZ_C + 255) / 256, 256, 0, stream>>>(row, cnt, eidx);

    // ---- conversions / weight transposes ----
    convbf_k<<<(NN * 32 + 255) / 256, 256, 0, stream>>>(X, Xbf, NN * 32);
    convbf_k<<<(ENUM * 32 + 255) / 256, 256, 0, stream>>>(E, Ebf, ENUM * 32);
    wtr_k<<<256, 256, 0, stream>>>(Wlin, WlinT, 512);
    wtr_k<<<64, 256, 0, stream>>>(Wn, WnT, 128);
    wtr_k<<<64, 256, 0, stream>>>(We, WeT, 128);

    // ---- dense pipeline ----
    gemm_mfma_k<true, false><<<dim3(1563, 2), 256, 0, stream>>>(Xbf, WnT, bn, nullptr, Xt, NN, 128);
    gemm_mfma_k<false, false><<<dim3(391, 2), 256, 0, stream>>>(Ebf, WeT, be, E, Eres, ENUM, 128);
    edge_agg_k<<<ENUM / 2, 256, 0, stream>>>(row, adjv, Xt, Eres);
    gemm_mfma_k<true, true><<<dim3(1563, 8), 256, 0, stream>>>(Xbf, WlinT, nullptr, nullptr, Xlin, NN, 512);
    convbf_k<<<(ENUM * 32 + 255) / 256, 256, 0, stream>>>(Eres, EresB, ENUM * 32);
    gemm_mfma_k<true, true><<<dim3(391, 8), 256, 0, stream>>>(EresB, WlinT, nullptr, nullptr, elin, ENUM, 512);

    // ---- attention dots ([r][f][h] layout) ----
    att_dot_fh_k<<<NN / 4, 256, 0, stream>>>(Xlin, att, ax, NN);
    att_dot_fh_k<<<ENUM / 4, 256, 0, stream>>>(elin, att + 128, ae, ENUM);

    // ---- CSR softmax (emits alpha k-order + alphag p-order; alphag overwrites EresB) ----
    softmax_csr_k<<<(NN * 4) / 256 + 1, 256, 0, stream>>>(rowptr, eidx, ax, ae, alpha, alphag);

    // ---- node -> hyperedge (out_e overwrites elin) ----
    out_e_k<<<ENUM / 4, 256, 0, stream>>>(row, alpha, Xlin, out_e);

    // ---- hyperedge -> node: atomic-free CSR gather ----
    xgather_k<<<NN / 4, 256, 0, stream>>>(rowptr, eidx, adjv, alphag, out_e, bias_conv, Xres);
}

// Round 6
// 307.617 us; speedup vs baseline: 1.2621x; 1.2621x over previous
//
#include <hip/hip_runtime.h>

#define NN 100000
#define ENUM 25000
#define NNZ_C 200000
// D = 128, H = 4, F = 128, Wlin: [128,512]
// Interleaved feature layout: [row][f][h] (f=0..127, h=0..3), via permuted WlinT rows.

typedef __attribute__((ext_vector_type(8))) short bf16x8;
typedef __attribute__((ext_vector_type(4))) float f32x4;

__device__ __forceinline__ float bf2f(unsigned short v) {
    return __uint_as_float(((unsigned)v) << 16);
}
__device__ __forceinline__ float blo(unsigned u) { return __uint_as_float(u << 16); }
__device__ __forceinline__ float bhi(unsigned u) { return __uint_as_float(u & 0xFFFF0000u); }
__device__ __forceinline__ unsigned short f2bf(float x) {
    unsigned u = __float_as_uint(x);
    unsigned r = (u + 0x7fff + ((u >> 16) & 1)) >> 16;   // round-to-nearest-even
    return (unsigned short)r;
}

// -------- f32 -> bf16 convert (4 elems/thread) --------
__global__ __launch_bounds__(256) void convbf_k(
    const float* __restrict__ in, unsigned short* __restrict__ out, int n4)
{
    const int t = blockIdx.x * 256 + threadIdx.x;
    if (t >= n4) return;
    const float4 a = ((const float4*)in)[t];
    ushort4 u;
    u.x = f2bf(a.x); u.y = f2bf(a.y); u.z = f2bf(a.z); u.w = f2bf(a.w);
    ((ushort4*)out)[t] = u;
}

// -------- W[128][NC] f32 -> Wt[cc][128] bf16; PERM: cc=(c&127)*4+(c>>7) --------
template <bool PERM>
__global__ __launch_bounds__(256) void wtr_k(
    const float* __restrict__ W, unsigned short* __restrict__ Wt, int NC)
{
    const int t = blockIdx.x * 256 + threadIdx.x;
    if (t >= 128 * NC) return;
    const int c = t % NC, k = t / NC;
    const int cc = PERM ? ((c & 127) * 4 + (c >> 7)) : c;
    Wt[cc * 128 + k] = f2bf(W[t]);
}

// ---------------- MFMA GEMM: C[M,NC] = A[M,128] @ Wt^T (+bias)(+resid) ----
template <bool BF16OUT>
__global__ __launch_bounds__(256) void gemm_mfma_k(
    const unsigned short* __restrict__ A, const unsigned short* __restrict__ Wt,
    const float* __restrict__ bias, const float* __restrict__ resid,
    void* __restrict__ Cv, int M, int NC)
{
    __shared__ unsigned short As[64 * 128];
    __shared__ unsigned short Bs[64 * 128];
    const int tid = threadIdx.x;
    const int r0 = blockIdx.x * 64;
    const int c0 = blockIdx.y * 64;

    {
        int rr = tid >> 4;
        const int kc = (tid & 15) * 8;
        #pragma unroll
        for (int it = 0; it < 4; it++) {
            int r = r0 + rr; if (r > M - 1) r = M - 1;
            const uint4 va = *(const uint4*)(A + (size_t)r * 128 + kc);
            const uint4 vb = *(const uint4*)(Wt + (size_t)(c0 + rr) * 128 + kc);
            const int idx = (rr * 128 + kc) ^ ((rr & 7) << 3);
            *(uint4*)&As[idx] = va;
            *(uint4*)&Bs[idx] = vb;
            rr += 16;
        }
    }
    __syncthreads();

    const int lane = tid & 63;
    const int wid = tid >> 6;
    const int wr = wid >> 1, wc = wid & 1;
    const int fr = lane & 15;
    const int kg = (lane >> 4) * 8;

    f32x4 acc[2][2] = {};

    #pragma unroll
    for (int ks = 0; ks < 4; ks++) {
        bf16x8 a[2], b[2];
        #pragma unroll
        for (int m = 0; m < 2; m++) {
            const int ar = wr * 32 + m * 16 + fr;
            const int idx = (ar * 128 + ks * 32 + kg) ^ ((ar & 7) << 3);
            a[m] = *(const bf16x8*)&As[idx];
        }
        #pragma unroll
        for (int n = 0; n < 2; n++) {
            const int br = wc * 32 + n * 16 + fr;
            const int idx = (br * 128 + ks * 32 + kg) ^ ((br & 7) << 3);
            b[n] = *(const bf16x8*)&Bs[idx];
        }
        #pragma unroll
        for (int m = 0; m < 2; m++)
            #pragma unroll
            for (int n = 0; n < 2; n++)
                acc[m][n] = __builtin_amdgcn_mfma_f32_16x16x32_bf16(a[m], b[n], acc[m][n], 0, 0, 0);
    }

    #pragma unroll
    for (int m = 0; m < 2; m++) {
        #pragma unroll
        for (int n = 0; n < 2; n++) {
            const int c = c0 + wc * 32 + n * 16 + (lane & 15);
            #pragma unroll
            for (int j = 0; j < 4; j++) {
                const int r = r0 + wr * 32 + m * 16 + (lane >> 4) * 4 + j;
                if (r < M) {
                    float v = acc[m][n][j];
                    if (bias) v += bias[c];
                    if (resid) v += resid[(size_t)r * NC + c];
                    if (BF16OUT) ((unsigned short*)Cv)[(size_t)r * NC + c] = f2bf(v);
                    else         ((float*)Cv)[(size_t)r * NC + c] = v;
                }
            }
        }
    }
}

// -------- edge aggregation: Eres[e,:] += (1/deg_e) * sum_j adj[k] * Xt[row[k],:] ----
__global__ __launch_bounds__(256) void edge_agg_k(
    const int* __restrict__ row, const float* __restrict__ adjv,
    const unsigned short* __restrict__ Xt, float* __restrict__ Eres)
{
    const int e = blockIdx.x * 2 + (threadIdx.x >> 7);
    const int f = threadIdx.x & 127;
    if (e >= ENUM) return;
    float acc = 0.f, deg = 0.f;
    #pragma unroll
    for (int j = 0; j < 8; j++) {
        const int k = e + j * ENUM;
        const float v = adjv[k];
        deg += v;
        acc += v * bf2f(Xt[(size_t)row[k] * 128 + f]);
    }
    Eres[(size_t)e * 128 + f] += acc / deg;
}

// -------- attention dot on [r][f][h] layout: one wave per row ----
__global__ __launch_bounds__(256) void att_dot_fh_k(
    const unsigned short* __restrict__ feat, const float* __restrict__ att,
    float* __restrict__ out, int M)
{
    const int r = blockIdx.x * 4 + (threadIdx.x >> 6);
    const int lane = threadIdx.x & 63;
    if (r >= M) return;
    const int f0 = lane * 2;
    const uint4 u = *(const uint4*)(feat + (size_t)r * 512 + f0 * 4);
    float s0 = blo(u.x) * att[f0]       + blo(u.z) * att[f0 + 1];
    float s1 = bhi(u.x) * att[256 + f0] + bhi(u.z) * att[256 + f0 + 1];
    float s2 = blo(u.y) * att[512 + f0] + blo(u.w) * att[512 + f0 + 1];
    float s3 = bhi(u.y) * att[768 + f0] + bhi(u.w) * att[768 + f0 + 1];
    #pragma unroll
    for (int off = 1; off < 64; off <<= 1) {
        s0 += __shfl_xor(s0, off);
        s1 += __shfl_xor(s1, off);
        s2 += __shfl_xor(s2, off);
        s3 += __shfl_xor(s3, off);
    }
    if (lane == 0) *(float4*)(out + (size_t)r * 4) = make_float4(s0, s1, s2, s3);
}

// -------- CSR build --------
__global__ __launch_bounds__(256) void zero_k(unsigned* __restrict__ p, int n)
{
    const int t = blockIdx.x * 256 + threadIdx.x;
    if (t < n) p[t] = 0u;
}

__global__ __launch_bounds__(256) void hist_k(
    const int* __restrict__ row, int* __restrict__ cnt)
{
    const int k = blockIdx.x * 256 + threadIdx.x;
    if (k < NNZ_C) atomicAdd(cnt + row[k], 1);
}

__global__ __launch_bounds__(256) void scan1_k(
    const int* __restrict__ cnt, int* __restrict__ rp, int* __restrict__ bsum, int n)
{
    __shared__ int sh[256];
    const int t = threadIdx.x, g = blockIdx.x * 256 + t;
    const int v = (g < n) ? cnt[g] : 0;
    sh[t] = v; __syncthreads();
    #pragma unroll
    for (int off = 1; off < 256; off <<= 1) {
        const int add = (t >= off) ? sh[t - off] : 0;
        __syncthreads();
        sh[t] += add;
        __syncthreads();
    }
    if (g < n) rp[g] = sh[t] - v;
    if (t == 255) bsum[blockIdx.x] = sh[255];
}

__global__ __launch_bounds__(512) void scan2_k(int* __restrict__ bsum, int nb)
{
    __shared__ int sh[512];
    const int t = threadIdx.x;
    const int v = (t < nb) ? bsum[t] : 0;
    sh[t] = v; __syncthreads();
    #pragma unroll
    for (int off = 1; off < 512; off <<= 1) {
        const int add = (t >= off) ? sh[t - off] : 0;
        __syncthreads();
        sh[t] += add;
        __syncthreads();
    }
    if (t < nb) bsum[t] = sh[t] - v;
}

__global__ __launch_bounds__(256) void scan3_k(
    int* __restrict__ rp, const int* __restrict__ bsum, int* __restrict__ cur, int n)
{
    const int g = blockIdx.x * 256 + threadIdx.x;
    if (g < n) {
        const int v = rp[g] + bsum[g >> 8];
        rp[g] = v;
        cur[g] = v;
    }
    if (g == 0) rp[n] = NNZ_C;
}

__global__ __launch_bounds__(256) void fill_k(
    const int* __restrict__ row, int* __restrict__ cur, int* __restrict__ eidx)
{
    const int k = blockIdx.x * 256 + threadIdx.x;
    if (k < NNZ_C) {
        const int p = atomicAdd(cur + row[k], 1);
        eidx[p] = k;
    }
}

// -------- CSR segment softmax; emits alpha (k-order) AND alphag (CSR p-order) ----
__global__ __launch_bounds__(256) void softmax_csr_k(
    const int* __restrict__ rowptr, const int* __restrict__ eidx,
    const float* __restrict__ ax, const float* __restrict__ ae,
    float* __restrict__ alpha, float* __restrict__ alphag)
{
    const int t = blockIdx.x * 256 + threadIdx.x;
    if (t >= NN * 4) return;
    const int r = t >> 2, h = t & 3;
    const int p0 = rowptr[r], p1 = rowptr[r + 1];
    if (p0 == p1) return;
    const float axv = ax[t];
    float m = -1e30f;
    for (int p = p0; p < p1; ++p) {
        const int c = eidx[p] % ENUM;           // col[k] == k % EN by construction
        float a = axv + ae[c * 4 + h];
        a = (a >= 0.f) ? a : 0.2f * a;
        m = fmaxf(m, a);
    }
    float s = 0.f;
    for (int p = p0; p < p1; ++p) {
        const int k = eidx[p];
        const int c = k % ENUM;
        float a = axv + ae[c * 4 + h];
        a = (a >= 0.f) ? a : 0.2f * a;
        const float e = __expf(a - m);
        s += e;
        alpha[(size_t)k * 4 + h] = e;
    }
    const float rs = 1.f / s;
    for (int p = p0; p < p1; ++p) {
        const int k = eidx[p];
        const float v = alpha[(size_t)k * 4 + h] * rs;
        alpha[(size_t)k * 4 + h] = v;
        alphag[((size_t)p << 2) | h] = v;
    }
}

// -------- out_e[e][f][h] = (1/8) sum_j alpha[k,h] * Xlin[row[k]][f][h]  (bf16) ----
__global__ __launch_bounds__(256) void out_e_k(
    const int* __restrict__ row, const float* __restrict__ alpha,
    const unsigned short* __restrict__ Xlin, unsigned short* __restrict__ out_e)
{
    const int e = blockIdx.x * 4 + (threadIdx.x >> 6);
    const int lane = threadIdx.x & 63;
    if (e >= ENUM) return;
    const int f0 = lane * 2;
    float a0 = 0.f, a1 = 0.f, a2 = 0.f, a3 = 0.f;
    float a4 = 0.f, a5 = 0.f, a6 = 0.f, a7 = 0.f;
    #pragma unroll
    for (int j = 0; j < 8; j++) {
        const int k = e + j * ENUM;
        const int r = row[k];
        const float4 al = *(const float4*)(alpha + (size_t)k * 4);
        const uint4 u = *(const uint4*)(Xlin + (size_t)r * 512 + f0 * 4);
        a0 += al.x * blo(u.x); a1 += al.y * bhi(u.x);
        a2 += al.z * blo(u.y); a3 += al.w * bhi(u.y);
        a4 += al.x * blo(u.z); a5 += al.y * bhi(u.z);
        a6 += al.z * blo(u.w); a7 += al.w * bhi(u.w);
    }
    uint4 o;
    o.x = (unsigned)f2bf(0.125f * a0) | ((unsigned)f2bf(0.125f * a1) << 16);
    o.y = (unsigned)f2bf(0.125f * a2) | ((unsigned)f2bf(0.125f * a3) << 16);
    o.z = (unsigned)f2bf(0.125f * a4) | ((unsigned)f2bf(0.125f * a5) << 16);
    o.w = (unsigned)f2bf(0.125f * a6) | ((unsigned)f2bf(0.125f * a7) << 16);
    *(uint4*)(out_e + (size_t)e * 512 + f0 * 4) = o;
}

// -------- final CSR gather: one wave per node, 2 f per lane, unroll-2 over edges ----
__global__ __launch_bounds__(256) void xgather_k(
    const int* __restrict__ rowptr, const int* __restrict__ eidx,
    const float* __restrict__ adjv, const float* __restrict__ alphag,
    const unsigned short* __restrict__ out_e, const float* __restrict__ bias,
    float* __restrict__ Xres)
{
    const int r = blockIdx.x * 4 + (threadIdx.x >> 6);
    const int lane = threadIdx.x & 63;
    if (r >= NN) return;
    const int p0 = rowptr[r], p1 = rowptr[r + 1];
    const int f0 = lane * 2;
    float a0 = 0.f, a1 = 0.f, ds = 0.f;

#define XG_BODY(P) {                                                          \
        const int k = eidx[P];                                                \
        const int c = k % ENUM;                                               \
        ds += adjv[c];                                                        \
        const float4 al = *(const float4*)(alphag + ((size_t)(P) << 2));      \
        const uint4 u = *(const uint4*)(out_e + (size_t)c * 512 + f0 * 4);    \
        a0 += al.x * blo(u.x) + al.y * bhi(u.x) + al.z * blo(u.y) + al.w * bhi(u.y); \
        a1 += al.x * blo(u.z) + al.y * bhi(u.z) + al.z * blo(u.w) + al.w * bhi(u.w); \
    }

    int p = p0;
    for (; p + 2 <= p1; p += 2) { XG_BODY(p); XG_BODY(p + 1); }
    if (p < p1) XG_BODY(p);
#undef XG_BODY

    const float w = (p1 > p0) ? 0.25f / ds : 0.f;
    float2 o;
    o.x = bias[f0] + w * a0;
    o.y = bias[f0 + 1] + w * a1;
    *(float2*)(Xres + (size_t)r * 128 + f0) = o;
}

extern "C" void kernel_launch(void* const* d_in, const int* in_sizes, int n_in,
                              void* d_out, int out_size, void* d_ws, size_t ws_size,
                              hipStream_t stream)
{
    const float* X         = (const float*)d_in[0];
    const float* E         = (const float*)d_in[1];
    const int*   adj       = (const int*)d_in[2];
    const float* adjv      = (const float*)d_in[3];
    const float* Wn        = (const float*)d_in[4];
    const float* bn        = (const float*)d_in[5];
    const float* We        = (const float*)d_in[6];
    const float* be        = (const float*)d_in[7];
    const float* Wlin      = (const float*)d_in[8];
    const float* att       = (const float*)d_in[9];
    const float* bias_conv = (const float*)d_in[10];
    const int* row = adj;

    float* Xres = (float*)d_out;
    float* Eres = Xres + (size_t)NN * 128;

    // workspace layout (~167 MB)
    char* wsb = (char*)d_ws;
    unsigned short* Xbf   = (unsigned short*)(wsb);              // [0, 25.6M)
    unsigned short* elin  = (unsigned short*)(wsb);              // aliases Xbf (after gemm4)
    unsigned short* out_e = (unsigned short*)(wsb);              // aliases elin (after att_dot_e)
    unsigned short* Xt    = (unsigned short*)(wsb + 25600000);   // [25.6M, 51.2M)
    unsigned short* EresB = (unsigned short*)(wsb + 25600000);   // aliases Xt (after edge_agg)
    float*          alphag= (float*)(wsb + 25600000);            // aliases EresB (after gemm5)
    unsigned short* Xlin  = (unsigned short*)(wsb + 51200000);   // 102.4 MB
    unsigned short* Ebf   = (unsigned short*)(wsb + 153600000);  // 6.4 MB
    unsigned short* WlinT = (unsigned short*)(wsb + 160000000);  // 128 KB (row-permuted)
    unsigned short* WnT   = (unsigned short*)(wsb + 160131072);  // 32 KB
    unsigned short* WeT   = (unsigned short*)(wsb + 160163840);  // 32 KB
    float* ax    = (float*)(wsb + 160196608);                    // 1.6 MB
    float* ae    = (float*)(wsb + 161796608);                    // 0.4 MB
    float* alpha = (float*)(wsb + 162196608);                    // 3.2 MB
    int* rowptr  = (int*)(wsb + 165396608);                      // 400,016 B
    int* cnt     = (int*)(wsb + 165796624);                      // 400,000 B (reused as cursor)
    int* eidx    = (int*)(wsb + 166196624);                      // 800,000 B
    int* bsum    = (int*)(wsb + 166996624);                      // 2 KB

    // ---- CSR build (independent of GEMMs) ----
    zero_k<<<(NN + 255) / 256, 256, 0, stream>>>((unsigned*)cnt, NN);
    hist_k<<<(NNZ_C + 255) / 256, 256, 0, stream>>>(row, cnt);
    scan1_k<<<(NN + 255) / 256, 256, 0, stream>>>(cnt, rowptr, bsum, NN);
    scan2_k<<<1, 512, 0, stream>>>(bsum, (NN + 255) / 256);
    scan3_k<<<(NN + 255) / 256, 256, 0, stream>>>(rowptr, bsum, cnt, NN);
    fill_k<<<(NNZ_C + 255) / 256, 256, 0, stream>>>(row, cnt, eidx);

    // ---- conversions / weight transposes ----
    convbf_k<<<(NN * 32 + 255) / 256, 256, 0, stream>>>(X, Xbf, NN * 32);
    convbf_k<<<(ENUM * 32 + 255) / 256, 256, 0, stream>>>(E, Ebf, ENUM * 32);
    wtr_k<true><<<256, 256, 0, stream>>>(Wlin, WlinT, 512);   // row-permuted: WlinT[cc]
    wtr_k<false><<<64, 256, 0, stream>>>(Wn, WnT, 128);
    wtr_k<false><<<64, 256, 0, stream>>>(We, WeT, 128);

    // ---- dense pipeline (all stores coalesced; Xlin/elin natively [r][f][h]) ----
    gemm_mfma_k<true><<<dim3(1563, 2), 256, 0, stream>>>(Xbf, WnT, bn, nullptr, Xt, NN, 128);
    gemm_mfma_k<false><<<dim3(391, 2), 256, 0, stream>>>(Ebf, WeT, be, E, Eres, ENUM, 128);
    edge_agg_k<<<ENUM / 2, 256, 0, stream>>>(row, adjv, Xt, Eres);
    gemm_mfma_k<true><<<dim3(1563, 8), 256, 0, stream>>>(Xbf, WlinT, nullptr, nullptr, Xlin, NN, 512);
    convbf_k<<<(ENUM * 32 + 255) / 256, 256, 0, stream>>>(Eres, EresB, ENUM * 32);
    gemm_mfma_k<true><<<dim3(391, 8), 256, 0, stream>>>(EresB, WlinT, nullptr, nullptr, elin, ENUM, 512);

    // ---- attention dots ([r][f][h] layout) ----
    att_dot_fh_k<<<NN / 4, 256, 0, stream>>>(Xlin, att, ax, NN);
    att_dot_fh_k<<<ENUM / 4, 256, 0, stream>>>(elin, att + 128, ae, ENUM);

    // ---- CSR softmax (emits alpha k-order + alphag p-order; alphag overwrites EresB) ----
    softmax_csr_k<<<(NN * 4) / 256 + 1, 256, 0, stream>>>(rowptr, eidx, ax, ae, alpha, alphag);

    // ---- node -> hyperedge (out_e overwrites elin) ----
    out_e_k<<<ENUM / 4, 256, 0, stream>>>(row, alpha, Xlin, out_e);

    // ---- hyperedge -> node: atomic-free CSR gather ----
    xgather_k<<<NN / 4, 256, 0, stream>>>(rowptr, eidx, adjv, alphag, out_e, bias_conv, Xres);
}

// Round 7
// 289.086 us; speedup vs baseline: 1.3430x; 1.0641x over previous
//
#include <hip/hip_runtime.h>

#define NN 100000
#define ENUM 25000
#define NNZ_C 200000
// D = 128, H = 4, F = 128, Wlin: [128,512]
// Xlin layout: [row][f][h] via row-permuted WlinT. ax = X@A1, ae = Eres@A2.

typedef __attribute__((ext_vector_type(8))) short bf16x8;
typedef __attribute__((ext_vector_type(4))) float f32x4;

__device__ __forceinline__ float blo(unsigned u) { return __uint_as_float(u << 16); }
__device__ __forceinline__ float bhi(unsigned u) { return __uint_as_float(u & 0xFFFF0000u); }
__device__ __forceinline__ unsigned short f2bf(float x) {
    unsigned u = __float_as_uint(x);
    unsigned r = (u + 0x7fff + ((u >> 16) & 1)) >> 16;   // RNE
    return (unsigned short)r;
}
__device__ __forceinline__ unsigned pack2(float a, float b) {
    return (unsigned)f2bf(a) | ((unsigned)f2bf(b) << 16);
}

// -------- W[128][NC] f32 -> Wt[cc][128] bf16; PERM: cc=(c&127)*4+(c>>7) --------
template <bool PERM>
__global__ __launch_bounds__(256) void wtr_k(
    const float* __restrict__ W, unsigned short* __restrict__ Wt, int NC)
{
    const int t = blockIdx.x * 256 + threadIdx.x;
    if (t >= 128 * NC) return;
    const int c = t % NC, k = t / NC;
    const int cc = PERM ? ((c & 127) * 4 + (c >> 7)) : c;
    Wt[cc * 128 + k] = f2bf(W[t]);
}

// -------- A1/A2[k][h] = sum_f Wlin[k][h*128+f] * att[h*256 + (pair?128:0) + f] ----
__global__ __launch_bounds__(256) void attw_k(
    const float* __restrict__ Wlin, const float* __restrict__ att,
    float* __restrict__ A1, float* __restrict__ A2)
{
    const int t = threadIdx.x;
    const int k = t & 127;
    const int pair = t >> 7;
    const float* wrow = Wlin + (size_t)k * 512;
    float s[4];
    #pragma unroll
    for (int h = 0; h < 4; h++) {
        float acc = 0.f;
        const float* ap = att + h * 256 + pair * 128;
        const float* wp = wrow + h * 128;
        for (int f = 0; f < 128; f++) acc += wp[f] * ap[f];
        s[h] = acc;
    }
    float* dst = (pair ? A2 : A1) + k * 4;
    dst[0] = s[0]; dst[1] = s[1]; dst[2] = s[2]; dst[3] = s[3];
}

// -------- axe[r][h] = X[r,:] @ A[:, h]   (one wave per row) --------
__global__ __launch_bounds__(256) void axdot_k(
    const float* __restrict__ X, const float* __restrict__ A,
    float* __restrict__ out, int M)
{
    const int r = blockIdx.x * 4 + (threadIdx.x >> 6);
    const int lane = threadIdx.x & 63;
    if (r >= M) return;
    const int f0 = lane * 2;
    const float2 x = *(const float2*)(X + (size_t)r * 128 + f0);
    const float4 a0 = *(const float4*)(A + f0 * 4);
    const float4 a1 = *(const float4*)(A + f0 * 4 + 4);
    float s0 = x.x * a0.x + x.y * a1.x;
    float s1 = x.x * a0.y + x.y * a1.y;
    float s2 = x.x * a0.z + x.y * a1.z;
    float s3 = x.x * a0.w + x.y * a1.w;
    #pragma unroll
    for (int off = 1; off < 64; off <<= 1) {
        s0 += __shfl_xor(s0, off);
        s1 += __shfl_xor(s1, off);
        s2 += __shfl_xor(s2, off);
        s3 += __shfl_xor(s3, off);
    }
    if (lane == 0) *(float4*)(out + (size_t)r * 4) = make_float4(s0, s1, s2, s3);
}

// ---------------- MFMA GEMM, A staged once, CT column tiles ----------------
// A: f32 (AF32) or bf16 row-major [M][128]; Wt: bf16 [CT*64][128]
template <bool BF16OUT, int CT, bool AF32>
__global__ __launch_bounds__(256) void gemm2_k(
    const void* __restrict__ Av, const unsigned short* __restrict__ Wt,
    const float* __restrict__ bias, const float* __restrict__ resid,
    void* __restrict__ Cv, int M)
{
    const int NC = CT * 64;
    __shared__ unsigned short As[64 * 128];
    __shared__ unsigned short Bs[64 * 128];
    const int tid = threadIdx.x;
    const int r0 = blockIdx.x * 64;

    // ---- stage A once ----
    {
        int rr = tid >> 4;
        const int kc = (tid & 15) * 8;
        #pragma unroll
        for (int it = 0; it < 4; it++) {
            int r = r0 + rr; if (r > M - 1) r = M - 1;
            uint4 va;
            if (AF32) {
                const float* ap = (const float*)Av + (size_t)r * 128 + kc;
                const float4 f0 = *(const float4*)ap;
                const float4 f1 = *(const float4*)(ap + 4);
                va.x = pack2(f0.x, f0.y); va.y = pack2(f0.z, f0.w);
                va.z = pack2(f1.x, f1.y); va.w = pack2(f1.z, f1.w);
            } else {
                va = *(const uint4*)((const unsigned short*)Av + (size_t)r * 128 + kc);
            }
            *(uint4*)&As[(rr * 128 + kc) ^ ((rr & 7) << 3)] = va;
            rr += 16;
        }
    }
    __syncthreads();

    const int lane = tid & 63;
    const int wid = tid >> 6;
    const int wr = wid >> 1, wc = wid & 1;
    const int fr = lane & 15;
    const int kg = (lane >> 4) * 8;

    // ---- hoist A fragments ----
    bf16x8 a[2][4];
    #pragma unroll
    for (int m = 0; m < 2; m++) {
        const int ar = wr * 32 + m * 16 + fr;
        #pragma unroll
        for (int ks = 0; ks < 4; ks++)
            a[m][ks] = *(const bf16x8*)&As[(ar * 128 + ks * 32 + kg) ^ ((ar & 7) << 3)];
    }

    for (int ct = 0; ct < CT; ct++) {
        const int c0 = ct * 64;
        __syncthreads();   // prior Bs reads complete
        {
            int rr = tid >> 4;
            const int kc = (tid & 15) * 8;
            #pragma unroll
            for (int it = 0; it < 4; it++) {
                const uint4 vb = *(const uint4*)(Wt + (size_t)(c0 + rr) * 128 + kc);
                *(uint4*)&Bs[(rr * 128 + kc) ^ ((rr & 7) << 3)] = vb;
                rr += 16;
            }
        }
        __syncthreads();

        f32x4 acc[2][2] = {};
        #pragma unroll
        for (int ks = 0; ks < 4; ks++) {
            bf16x8 b[2];
            #pragma unroll
            for (int n = 0; n < 2; n++) {
                const int br = wc * 32 + n * 16 + fr;
                b[n] = *(const bf16x8*)&Bs[(br * 128 + ks * 32 + kg) ^ ((br & 7) << 3)];
            }
            #pragma unroll
            for (int m = 0; m < 2; m++)
                #pragma unroll
                for (int n = 0; n < 2; n++)
                    acc[m][n] = __builtin_amdgcn_mfma_f32_16x16x32_bf16(a[m][ks], b[n], acc[m][n], 0, 0, 0);
        }

        #pragma unroll
        for (int m = 0; m < 2; m++) {
            #pragma unroll
            for (int n = 0; n < 2; n++) {
                const int c = c0 + wc * 32 + n * 16 + (lane & 15);
                #pragma unroll
                for (int j = 0; j < 4; j++) {
                    const int r = r0 + wr * 32 + m * 16 + (lane >> 4) * 4 + j;
                    if (r < M) {
                        float v = acc[m][n][j];
                        if (bias) v += bias[c];
                        if (resid) v += resid[(size_t)r * NC + c];
                        if (BF16OUT) ((unsigned short*)Cv)[(size_t)r * NC + c] = f2bf(v);
                        else         ((float*)Cv)[(size_t)r * NC + c] = v;
                    }
                }
            }
        }
    }
}

// -------- edge aggregation: Eres[e,:] += (1/deg_e) * sum_j adj[k] * Xt[row[k],:] ----
__global__ __launch_bounds__(256) void edge_agg_k(
    const int* __restrict__ row, const float* __restrict__ adjv,
    const unsigned short* __restrict__ Xt, float* __restrict__ Eres)
{
    const int e = blockIdx.x * 2 + (threadIdx.x >> 7);
    const int f = threadIdx.x & 127;
    if (e >= ENUM) return;
    float acc = 0.f, deg = 0.f;
    #pragma unroll
    for (int j = 0; j < 8; j++) {
        const int k = e + j * ENUM;
        const float v = adjv[k];
        deg += v;
        acc += v * blo(Xt[(size_t)row[k] * 128 + f]);
    }
    Eres[(size_t)e * 128 + f] += acc / deg;
}

// -------- CSR build --------
__global__ __launch_bounds__(256) void zero_k(unsigned* __restrict__ p, int n)
{
    const int t = blockIdx.x * 256 + threadIdx.x;
    if (t < n) p[t] = 0u;
}

__global__ __launch_bounds__(256) void hist_k(
    const int* __restrict__ row, int* __restrict__ cnt)
{
    const int k = blockIdx.x * 256 + threadIdx.x;
    if (k < NNZ_C) atomicAdd(cnt + row[k], 1);
}

__global__ __launch_bounds__(256) void scan1_k(
    const int* __restrict__ cnt, int* __restrict__ rp, int* __restrict__ bsum, int n)
{
    __shared__ int sh[256];
    const int t = threadIdx.x, g = blockIdx.x * 256 + t;
    const int v = (g < n) ? cnt[g] : 0;
    sh[t] = v; __syncthreads();
    #pragma unroll
    for (int off = 1; off < 256; off <<= 1) {
        const int add = (t >= off) ? sh[t - off] : 0;
        __syncthreads();
        sh[t] += add;
        __syncthreads();
    }
    if (g < n) rp[g] = sh[t] - v;
    if (t == 255) bsum[blockIdx.x] = sh[255];
}

__global__ __launch_bounds__(512) void scan2_k(int* __restrict__ bsum, int nb)
{
    __shared__ int sh[512];
    const int t = threadIdx.x;
    const int v = (t < nb) ? bsum[t] : 0;
    sh[t] = v; __syncthreads();
    #pragma unroll
    for (int off = 1; off < 512; off <<= 1) {
        const int add = (t >= off) ? sh[t - off] : 0;
        __syncthreads();
        sh[t] += add;
        __syncthreads();
    }
    if (t < nb) bsum[t] = sh[t] - v;
}

__global__ __launch_bounds__(256) void scan3_k(
    int* __restrict__ rp, const int* __restrict__ bsum, int* __restrict__ cur, int n)
{
    const int g = blockIdx.x * 256 + threadIdx.x;
    if (g < n) {
        const int v = rp[g] + bsum[g >> 8];
        rp[g] = v;
        cur[g] = v;
    }
    if (g == 0) rp[n] = NNZ_C;
}

__global__ __launch_bounds__(256) void fill_k(
    const int* __restrict__ row, int* __restrict__ cur, int* __restrict__ eidx)
{
    const int k = blockIdx.x * 256 + threadIdx.x;
    if (k < NNZ_C) {
        const int p = atomicAdd(cur + row[k], 1);
        eidx[p] = k;
    }
}

// -------- CSR segment softmax; emits alpha (k-order) AND alphag (CSR p-order) ----
__global__ __launch_bounds__(256) void softmax_csr_k(
    const int* __restrict__ rowptr, const int* __restrict__ eidx,
    const float* __restrict__ ax, const float* __restrict__ ae,
    float* __restrict__ alpha, float* __restrict__ alphag)
{
    const int t = blockIdx.x * 256 + threadIdx.x;
    if (t >= NN * 4) return;
    const int r = t >> 2, h = t & 3;
    const int p0 = rowptr[r], p1 = rowptr[r + 1];
    if (p0 == p1) return;
    const float axv = ax[t];
    float m = -1e30f;
    for (int p = p0; p < p1; ++p) {
        const int c = eidx[p] % ENUM;           // col[k] == k % EN by construction
        float a = axv + ae[c * 4 + h];
        a = (a >= 0.f) ? a : 0.2f * a;
        m = fmaxf(m, a);
    }
    float s = 0.f;
    for (int p = p0; p < p1; ++p) {
        const int k = eidx[p];
        const int c = k % ENUM;
        float a = axv + ae[c * 4 + h];
        a = (a >= 0.f) ? a : 0.2f * a;
        const float e = __expf(a - m);
        s += e;
        alpha[(size_t)k * 4 + h] = e;
    }
    const float rs = 1.f / s;
    for (int p = p0; p < p1; ++p) {
        const int k = eidx[p];
        const float v = alpha[(size_t)k * 4 + h] * rs;
        alpha[(size_t)k * 4 + h] = v;
        alphag[((size_t)p << 2) | h] = v;
    }
}

// -------- out_e[e][f][h] = (1/8) sum_j alpha[k,h] * Xlin[row[k]][f][h]  (bf16) ----
__global__ __launch_bounds__(256) void out_e_k(
    const int* __restrict__ row, const float* __restrict__ alpha,
    const unsigned short* __restrict__ Xlin, unsigned short* __restrict__ out_e)
{
    const int e = blockIdx.x * 4 + (threadIdx.x >> 6);
    const int lane = threadIdx.x & 63;
    if (e >= ENUM) return;
    const int f0 = lane * 2;
    float a0 = 0.f, a1 = 0.f, a2 = 0.f, a3 = 0.f;
    float a4 = 0.f, a5 = 0.f, a6 = 0.f, a7 = 0.f;
    #pragma unroll
    for (int j = 0; j < 8; j++) {
        const int k = e + j * ENUM;
        const int r = row[k];
        const float4 al = *(const float4*)(alpha + (size_t)k * 4);
        const uint4 u = *(const uint4*)(Xlin + (size_t)r * 512 + f0 * 4);
        a0 += al.x * blo(u.x); a1 += al.y * bhi(u.x);
        a2 += al.z * blo(u.y); a3 += al.w * bhi(u.y);
        a4 += al.x * blo(u.z); a5 += al.y * bhi(u.z);
        a6 += al.z * blo(u.w); a7 += al.w * bhi(u.w);
    }
    uint4 o;
    o.x = pack2(0.125f * a0, 0.125f * a1);
    o.y = pack2(0.125f * a2, 0.125f * a3);
    o.z = pack2(0.125f * a4, 0.125f * a5);
    o.w = pack2(0.125f * a6, 0.125f * a7);
    *(uint4*)(out_e + (size_t)e * 512 + f0 * 4) = o;
}

// -------- final CSR gather: one wave per node, 2 f per lane, unroll-2 over edges ----
__global__ __launch_bounds__(256) void xgather_k(
    const int* __restrict__ rowptr, const int* __restrict__ eidx,
    const float* __restrict__ adjv, const float* __restrict__ alphag,
    const unsigned short* __restrict__ out_e, const float* __restrict__ bias,
    float* __restrict__ Xres)
{
    const int r = blockIdx.x * 4 + (threadIdx.x >> 6);
    const int lane = threadIdx.x & 63;
    if (r >= NN) return;
    const int p0 = rowptr[r], p1 = rowptr[r + 1];
    const int f0 = lane * 2;
    float a0 = 0.f, a1 = 0.f, ds = 0.f;

#define XG_BODY(P) {                                                          \
        const int k = eidx[P];                                                \
        const int c = k % ENUM;                                               \
        ds += adjv[c];                                                        \
        const float4 al = *(const float4*)(alphag + ((size_t)(P) << 2));      \
        const uint4 u = *(const uint4*)(out_e + (size_t)c * 512 + f0 * 4);    \
        a0 += al.x * blo(u.x) + al.y * bhi(u.x) + al.z * blo(u.y) + al.w * bhi(u.y); \
        a1 += al.x * blo(u.z) + al.y * bhi(u.z) + al.z * blo(u.w) + al.w * bhi(u.w); \
    }

    int p = p0;
    for (; p + 2 <= p1; p += 2) { XG_BODY(p); XG_BODY(p + 1); }
    if (p < p1) XG_BODY(p);
#undef XG_BODY

    const float w = (p1 > p0) ? 0.25f / ds : 0.f;
    float2 o;
    o.x = bias[f0] + w * a0;
    o.y = bias[f0 + 1] + w * a1;
    *(float2*)(Xres + (size_t)r * 128 + f0) = o;
}

extern "C" void kernel_launch(void* const* d_in, const int* in_sizes, int n_in,
                              void* d_out, int out_size, void* d_ws, size_t ws_size,
                              hipStream_t stream)
{
    const float* X         = (const float*)d_in[0];
    const float* E         = (const float*)d_in[1];
    const int*   adj       = (const int*)d_in[2];
    const float* adjv      = (const float*)d_in[3];
    const float* Wn        = (const float*)d_in[4];
    const float* bn        = (const float*)d_in[5];
    const float* We        = (const float*)d_in[6];
    const float* be        = (const float*)d_in[7];
    const float* Wlin      = (const float*)d_in[8];
    const float* att       = (const float*)d_in[9];
    const float* bias_conv = (const float*)d_in[10];
    const int* row = adj;

    float* Xres = (float*)d_out;
    float* Eres = Xres + (size_t)NN * 128;

    // workspace layout (~161 MB)
    char* wsb = (char*)d_ws;
    unsigned short* out_e = (unsigned short*)(wsb);              // 25.6 MB
    unsigned short* Xt    = (unsigned short*)(wsb + 25600000);   // 25.6 MB (dead after edge_agg)
    float*          alphag= (float*)(wsb + 25600000);            // aliases Xt
    unsigned short* Xlin  = (unsigned short*)(wsb + 51200000);   // 102.4 MB
    unsigned short* WlinT = (unsigned short*)(wsb + 153600000);  // 128 KB (row-permuted)
    unsigned short* WnT   = (unsigned short*)(wsb + 153731072);  // 32 KB
    unsigned short* WeT   = (unsigned short*)(wsb + 153763840);  // 32 KB
    float* A1    = (float*)(wsb + 153796608);                    // 2 KB
    float* A2    = (float*)(wsb + 153798656);                    // 2 KB
    float* ax    = (float*)(wsb + 153800704);                    // 1.6 MB
    float* ae    = (float*)(wsb + 155400704);                    // 0.4 MB
    float* alpha = (float*)(wsb + 155800704);                    // 3.2 MB
    int* rowptr  = (int*)(wsb + 159000704);                      // 400,016 B
    int* cnt     = (int*)(wsb + 159400720);                      // 400,000 B
    int* eidx    = (int*)(wsb + 159800720);                      // 800,000 B
    int* bsum    = (int*)(wsb + 160600720);                      // 2 KB

    // ---- CSR build ----
    zero_k<<<(NN + 255) / 256, 256, 0, stream>>>((unsigned*)cnt, NN);
    hist_k<<<(NNZ_C + 255) / 256, 256, 0, stream>>>(row, cnt);
    scan1_k<<<(NN + 255) / 256, 256, 0, stream>>>(cnt, rowptr, bsum, NN);
    scan2_k<<<1, 512, 0, stream>>>(bsum, (NN + 255) / 256);
    scan3_k<<<(NN + 255) / 256, 256, 0, stream>>>(rowptr, bsum, cnt, NN);
    fill_k<<<(NNZ_C + 255) / 256, 256, 0, stream>>>(row, cnt, eidx);

    // ---- weight prep ----
    wtr_k<true><<<256, 256, 0, stream>>>(Wlin, WlinT, 512);
    wtr_k<false><<<64, 256, 0, stream>>>(Wn, WnT, 128);
    wtr_k<false><<<64, 256, 0, stream>>>(We, WeT, 128);
    attw_k<<<1, 256, 0, stream>>>(Wlin, att, A1, A2);

    // ---- dense pipeline (A read f32, staged once, CT col-tiles) ----
    gemm2_k<true, 2, true><<<1563, 256, 0, stream>>>(X, WnT, bn, nullptr, Xt, NN);
    gemm2_k<false, 2, true><<<391, 256, 0, stream>>>(E, WeT, be, E, Eres, ENUM);
    edge_agg_k<<<ENUM / 2, 256, 0, stream>>>(row, adjv, Xt, Eres);
    gemm2_k<true, 8, true><<<1563, 256, 0, stream>>>(X, WlinT, nullptr, nullptr, Xlin, NN);

    // ---- attention logits (fused weights) ----
    axdot_k<<<NN / 4, 256, 0, stream>>>(X, A1, ax, NN);
    axdot_k<<<ENUM / 4, 256, 0, stream>>>(Eres, A2, ae, ENUM);

    // ---- CSR softmax ----
    softmax_csr_k<<<(NN * 4) / 256 + 1, 256, 0, stream>>>(rowptr, eidx, ax, ae, alpha, alphag);

    // ---- node -> hyperedge ----
    out_e_k<<<ENUM / 4, 256, 0, stream>>>(row, alpha, Xlin, out_e);

    // ---- hyperedge -> node ----
    xgather_k<<<NN / 4, 256, 0, stream>>>(rowptr, eidx, adjv, alphag, out_e, bias_conv, Xres);
}